// Round 1
// baseline (1136.367 us; speedup 1.0000x reference)
//
#include <hip/hip_runtime.h>
#include <stdint.h>
#include <math.h>

#define B_  4
#define S_  2048
#define H_  2048
#define NH_ 16
#define HD_ 128
#define M_  (B_*S_)     // 8192 rows
#define N3_ (3*H_)      // 6144

typedef __attribute__((ext_vector_type(8))) short short8;
typedef __attribute__((ext_vector_type(4))) float floatx4;

__device__ __forceinline__ unsigned short f2bf(float f) {
  unsigned u = __float_as_uint(f);
  u += 0x7FFF + ((u >> 16) & 1);          // round-to-nearest-even
  return (unsigned short)(u >> 16);
}

// ---------------------------------------------------------------- LayerNorm
__global__ __launch_bounds__(256) void ln_kernel(
    const float* __restrict__ x, const float* __restrict__ w,
    const float* __restrict__ b, unsigned short* __restrict__ xn) {
  int row = blockIdx.x;
  int t = threadIdx.x;
  const float* xr = x + (size_t)row * H_;
  float4 v0 = *(const float4*)(xr + t * 4);
  float4 v1 = *(const float4*)(xr + 1024 + t * 4);
  float s  = v0.x + v0.y + v0.z + v0.w + v1.x + v1.y + v1.z + v1.w;
  float sq = v0.x*v0.x + v0.y*v0.y + v0.z*v0.z + v0.w*v0.w
           + v1.x*v1.x + v1.y*v1.y + v1.z*v1.z + v1.w*v1.w;
  #pragma unroll
  for (int m = 32; m; m >>= 1) { s += __shfl_xor(s, m); sq += __shfl_xor(sq, m); }
  __shared__ float red[8];
  int wv = t >> 6;
  if ((t & 63) == 0) { red[wv * 2] = s; red[wv * 2 + 1] = sq; }
  __syncthreads();
  s  = red[0] + red[2] + red[4] + red[6];
  sq = red[1] + red[3] + red[5] + red[7];
  float mu  = s * (1.0f / H_);
  float var = sq * (1.0f / H_) - mu * mu;
  float rs  = rsqrtf(var + 1e-5f);

  float4 w0 = *(const float4*)(w + t * 4);
  float4 b0 = *(const float4*)(b + t * 4);
  float4 w1 = *(const float4*)(w + 1024 + t * 4);
  float4 b1 = *(const float4*)(b + 1024 + t * 4);
  ushort4 o0, o1;
  o0.x = f2bf((v0.x - mu) * rs * w0.x + b0.x);
  o0.y = f2bf((v0.y - mu) * rs * w0.y + b0.y);
  o0.z = f2bf((v0.z - mu) * rs * w0.z + b0.z);
  o0.w = f2bf((v0.w - mu) * rs * w0.w + b0.w);
  o1.x = f2bf((v1.x - mu) * rs * w1.x + b1.x);
  o1.y = f2bf((v1.y - mu) * rs * w1.y + b1.y);
  o1.z = f2bf((v1.z - mu) * rs * w1.z + b1.z);
  o1.w = f2bf((v1.w - mu) * rs * w1.w + b1.w);
  unsigned short* orow = xn + (size_t)row * H_;
  *(ushort4*)(orow + t * 4) = o0;
  *(ushort4*)(orow + 1024 + t * 4) = o1;
}

// ------------------------------------------- fp32 [R][C] -> bf16 [C][R] (Wt)
__global__ __launch_bounds__(256) void transpose_f2b(
    const float* __restrict__ in, unsigned short* __restrict__ out,
    int R, int C) {
  __shared__ float tile[32][33];
  int tx = threadIdx.x & 31, ty = threadIdx.x >> 5;   // ty 0..7
  int c0 = blockIdx.x * 32, r0 = blockIdx.y * 32;
  #pragma unroll
  for (int i = 0; i < 32; i += 8)
    tile[ty + i][tx] = in[(size_t)(r0 + ty + i) * C + c0 + tx];
  __syncthreads();
  #pragma unroll
  for (int i = 0; i < 32; i += 8)
    out[(size_t)(c0 + ty + i) * R + r0 + tx] = f2bf(tile[tx][ty + i]);
}

// ---------------------------------------------------------------- QKV GEMM
// A = xn [M][H] bf16 row-major; Bt = Wt [N3][H] bf16 (pre-transposed).
// Epilogue: +bias, scatter Q,K -> [BH][S][HD], V -> transposed [BH][HD][S].
__global__ __launch_bounds__(256) void qkv_gemm(
    const unsigned short* __restrict__ A, const unsigned short* __restrict__ Bt,
    const float* __restrict__ bias,
    unsigned short* __restrict__ qw, unsigned short* __restrict__ kw,
    unsigned short* __restrict__ vtw) {
  __shared__ unsigned short As[128 * 72];
  __shared__ unsigned short Bs[128 * 72];
  int n0 = blockIdx.x * 128, m0 = blockIdx.y * 128;
  int t = threadIdx.x, lane = t & 63, wv = t >> 6;
  int l15 = lane & 15, quad = lane >> 4;
  int wm = wv >> 1, wn = wv & 1;
  floatx4 acc[4][4];
  #pragma unroll
  for (int i = 0; i < 4; i++)
    #pragma unroll
    for (int j = 0; j < 4; j++) acc[i][j] = (floatx4){0.f, 0.f, 0.f, 0.f};

  int sr = t >> 3, sc = (t & 7) * 8;
  for (int k0 = 0; k0 < H_; k0 += 64) {
    __syncthreads();
    #pragma unroll
    for (int c = 0; c < 4; c++) {
      int row = c * 32 + sr;
      *(short8*)(As + row * 72 + sc) =
          *(const short8*)(A + (size_t)(m0 + row) * H_ + k0 + sc);
      *(short8*)(Bs + row * 72 + sc) =
          *(const short8*)(Bt + (size_t)(n0 + row) * H_ + k0 + sc);
    }
    __syncthreads();
    #pragma unroll
    for (int ks = 0; ks < 2; ks++) {
      short8 af[4], bf[4];
      #pragma unroll
      for (int i = 0; i < 4; i++)
        af[i] = *(const short8*)(As + (wm * 64 + i * 16 + l15) * 72 + ks * 32 + quad * 8);
      #pragma unroll
      for (int j = 0; j < 4; j++)
        bf[j] = *(const short8*)(Bs + (wn * 64 + j * 16 + l15) * 72 + ks * 32 + quad * 8);
      #pragma unroll
      for (int i = 0; i < 4; i++)
        #pragma unroll
        for (int j = 0; j < 4; j++)
          acc[i][j] = __builtin_amdgcn_mfma_f32_16x16x32_bf16(af[i], bf[j], acc[i][j], 0, 0, 0);
    }
  }
  int sec = n0 >> 11;              // 0:Q 1:K 2:V (block never straddles)
  int h = (n0 >> 7) & 15;          // head (block never straddles)
  #pragma unroll
  for (int j = 0; j < 4; j++) {
    int d = wn * 64 + j * 16 + l15;
    float bval = bias[n0 + d];
    #pragma unroll
    for (int i = 0; i < 4; i++) {
      #pragma unroll
      for (int reg = 0; reg < 4; reg++) {
        int m = m0 + wm * 64 + i * 16 + quad * 4 + reg;
        unsigned short bv = f2bf(acc[i][j][reg] + bval);
        int bb = m >> 11, s = m & 2047;
        int bh = bb * NH_ + h;
        if (sec == 0)      qw[((size_t)bh * S_ + s) * HD_ + d] = bv;
        else if (sec == 1) kw[((size_t)bh * S_ + s) * HD_ + d] = bv;
        else               vtw[((size_t)bh * HD_ + d) * S_ + s] = bv;
      }
    }
  }
}

// ----------------------------------------------------------- Proj GEMM + res
__global__ __launch_bounds__(256) void proj_gemm(
    const unsigned short* __restrict__ A, const unsigned short* __restrict__ Bt,
    const float* __restrict__ bias, const float* __restrict__ resid,
    float* __restrict__ out) {
  __shared__ unsigned short As[128 * 72];
  __shared__ unsigned short Bs[128 * 72];
  int n0 = blockIdx.x * 128, m0 = blockIdx.y * 128;
  int t = threadIdx.x, lane = t & 63, wv = t >> 6;
  int l15 = lane & 15, quad = lane >> 4;
  int wm = wv >> 1, wn = wv & 1;
  floatx4 acc[4][4];
  #pragma unroll
  for (int i = 0; i < 4; i++)
    #pragma unroll
    for (int j = 0; j < 4; j++) acc[i][j] = (floatx4){0.f, 0.f, 0.f, 0.f};

  int sr = t >> 3, sc = (t & 7) * 8;
  for (int k0 = 0; k0 < H_; k0 += 64) {
    __syncthreads();
    #pragma unroll
    for (int c = 0; c < 4; c++) {
      int row = c * 32 + sr;
      *(short8*)(As + row * 72 + sc) =
          *(const short8*)(A + (size_t)(m0 + row) * H_ + k0 + sc);
      *(short8*)(Bs + row * 72 + sc) =
          *(const short8*)(Bt + (size_t)(n0 + row) * H_ + k0 + sc);
    }
    __syncthreads();
    #pragma unroll
    for (int ks = 0; ks < 2; ks++) {
      short8 af[4], bf[4];
      #pragma unroll
      for (int i = 0; i < 4; i++)
        af[i] = *(const short8*)(As + (wm * 64 + i * 16 + l15) * 72 + ks * 32 + quad * 8);
      #pragma unroll
      for (int j = 0; j < 4; j++)
        bf[j] = *(const short8*)(Bs + (wn * 64 + j * 16 + l15) * 72 + ks * 32 + quad * 8);
      #pragma unroll
      for (int i = 0; i < 4; i++)
        #pragma unroll
        for (int j = 0; j < 4; j++)
          acc[i][j] = __builtin_amdgcn_mfma_f32_16x16x32_bf16(af[i], bf[j], acc[i][j], 0, 0, 0);
    }
  }
  #pragma unroll
  for (int j = 0; j < 4; j++) {
    int n = n0 + wn * 64 + j * 16 + l15;
    float bval = bias[n];
    #pragma unroll
    for (int i = 0; i < 4; i++) {
      #pragma unroll
      for (int reg = 0; reg < 4; reg++) {
        int m = m0 + wm * 64 + i * 16 + quad * 4 + reg;
        out[(size_t)m * H_ + n] = acc[i][j][reg] + bval + resid[(size_t)m * H_ + n];
      }
    }
  }
}

// ------------------------------------------------------- causal flash attn
// q,k: [BH][S][HD] bf16; vt: [BH][HD][S] bf16; out: [B][S][H] bf16 (merged)
__global__ __launch_bounds__(256) void attn_kernel(
    const unsigned short* __restrict__ qw, const unsigned short* __restrict__ kw,
    const unsigned short* __restrict__ vtw, unsigned short* __restrict__ ow) {
  __shared__ unsigned short Klds[64 * 136];
  __shared__ unsigned short Vt[128 * 72];
  __shared__ unsigned short Pl[4][16 * 72];
  int qt = blockIdx.x, bh = blockIdx.y;
  int t = threadIdx.x, lane = t & 63, wv = t >> 6;
  int l15 = lane & 15, quad = lane >> 4;
  int qb = qt * 64;
  int qr = qb + wv * 16;                     // wave's 16 q-rows start

  short8 qf[4];
  const unsigned short* qbase = qw + ((size_t)bh * S_ + qr + l15) * HD_;
  #pragma unroll
  for (int ks = 0; ks < 4; ks++)
    qf[ks] = *(const short8*)(qbase + ks * 32 + quad * 8);

  float m_i[4], l_i[4];
  floatx4 o[8];
  #pragma unroll
  for (int r = 0; r < 4; r++) { m_i[r] = -INFINITY; l_i[r] = 0.f; }
  #pragma unroll
  for (int ht = 0; ht < 8; ht++) o[ht] = (floatx4){0.f, 0.f, 0.f, 0.f};

  const float scale = 0.08838834764831845f;
  int krr = t >> 4, kcc = (t & 15) * 8;      // K staging: 16 lanes/row
  int vdd = t >> 3, vss = (t & 7) * 8;       // Vt staging: 8 lanes/row

  for (int kt = 0; kt <= qt; kt++) {
    int kb = kt * 64;
    #pragma unroll
    for (int c = 0; c < 4; c++) {
      int row = c * 16 + krr;
      *(short8*)(Klds + row * 136 + kcc) =
          *(const short8*)(kw + ((size_t)bh * S_ + kb + row) * HD_ + kcc);
      int d = c * 32 + vdd;
      *(short8*)(Vt + d * 72 + vss) =
          *(const short8*)(vtw + ((size_t)bh * HD_ + d) * S_ + kb + vss);
    }
    __syncthreads();

    floatx4 sv[4];
    #pragma unroll
    for (int j = 0; j < 4; j++) {
      sv[j] = (floatx4){0.f, 0.f, 0.f, 0.f};
      #pragma unroll
      for (int ks = 0; ks < 4; ks++) {
        short8 kf = *(const short8*)(Klds + (j * 16 + l15) * 136 + ks * 32 + quad * 8);
        sv[j] = __builtin_amdgcn_mfma_f32_16x16x32_bf16(qf[ks], kf, sv[j], 0, 0, 0);
      }
    }

    #pragma unroll
    for (int reg = 0; reg < 4; reg++) {
      int grow = qr + quad * 4 + reg;
      float p[4];
      float mx = m_i[reg];
      #pragma unroll
      for (int j = 0; j < 4; j++) {
        float v = sv[j][reg] * scale;
        int gcol = kb + j * 16 + l15;
        if (gcol > grow) v = -1e30f;
        p[j] = v;
        mx = fmaxf(mx, v);
      }
      #pragma unroll
      for (int msk = 8; msk; msk >>= 1) mx = fmaxf(mx, __shfl_xor(mx, msk));
      float sum = 0.f;
      #pragma unroll
      for (int j = 0; j < 4; j++) { p[j] = __expf(p[j] - mx); sum += p[j]; }
      #pragma unroll
      for (int msk = 8; msk; msk >>= 1) sum += __shfl_xor(sum, msk);
      float alpha = __expf(m_i[reg] - mx);
      l_i[reg] = l_i[reg] * alpha + sum;
      m_i[reg] = mx;
      #pragma unroll
      for (int ht = 0; ht < 8; ht++) o[ht][reg] *= alpha;
      #pragma unroll
      for (int j = 0; j < 4; j++)
        Pl[wv][(quad * 4 + reg) * 72 + j * 16 + l15] = f2bf(p[j]);
    }

    #pragma unroll
    for (int ks = 0; ks < 2; ks++) {
      short8 pf = *(const short8*)(&Pl[wv][l15 * 72 + ks * 32 + quad * 8]);
      #pragma unroll
      for (int ht = 0; ht < 8; ht++) {
        short8 vf = *(const short8*)(Vt + (ht * 16 + l15) * 72 + ks * 32 + quad * 8);
        o[ht] = __builtin_amdgcn_mfma_f32_16x16x32_bf16(pf, vf, o[ht], 0, 0, 0);
      }
    }
    __syncthreads();
  }

  int h = bh & 15, bb = bh >> 4;
  #pragma unroll
  for (int reg = 0; reg < 4; reg++) {
    float inv = 1.0f / l_i[reg];
    int s = qr + quad * 4 + reg;
    size_t base = ((size_t)(bb * S_ + s)) * H_ + h * HD_;
    #pragma unroll
    for (int ht = 0; ht < 8; ht++)
      ow[base + ht * 16 + l15] = f2bf(o[ht][reg] * inv);
  }
}

// ---------------------------------------------------------------- launcher
extern "C" void kernel_launch(void* const* d_in, const int* in_sizes, int n_in,
                              void* d_out, int out_size, void* d_ws, size_t ws_size,
                              hipStream_t stream) {
  (void)in_sizes; (void)n_in; (void)out_size; (void)ws_size;
  const float* x      = (const float*)d_in[0];
  const float* ln_w   = (const float*)d_in[1];
  const float* ln_b   = (const float*)d_in[2];
  const float* attn_w = (const float*)d_in[3];
  const float* attn_b = (const float*)d_in[4];
  const float* proj_w = (const float*)d_in[5];
  const float* proj_b = (const float*)d_in[6];
  float* out = (float*)d_out;

  char* ws = (char*)d_ws;
  size_t off = 0;
  auto alloc = [&](size_t bytes) {
    char* p = ws + off;
    off += (bytes + 255) & ~(size_t)255;
    return p;
  };
  unsigned short* xn     = (unsigned short*)alloc((size_t)M_ * H_ * 2);
  unsigned short* wqkvt  = (unsigned short*)alloc((size_t)N3_ * H_ * 2);
  unsigned short* wprojt = (unsigned short*)alloc((size_t)H_ * H_ * 2);
  unsigned short* qws    = (unsigned short*)alloc((size_t)M_ * H_ * 2);
  unsigned short* kws    = (unsigned short*)alloc((size_t)M_ * H_ * 2);
  unsigned short* vtws   = (unsigned short*)alloc((size_t)M_ * H_ * 2);
  unsigned short* attn_out = xn;   // xn dead after qkv_gemm — alias

  ln_kernel<<<M_, 256, 0, stream>>>(x, ln_w, ln_b, xn);
  transpose_f2b<<<dim3(N3_ / 32, H_ / 32), 256, 0, stream>>>(attn_w, wqkvt, H_, N3_);
  transpose_f2b<<<dim3(H_ / 32, H_ / 32), 256, 0, stream>>>(proj_w, wprojt, H_, H_);
  qkv_gemm<<<dim3(N3_ / 128, M_ / 128), 256, 0, stream>>>(xn, wqkvt, attn_b, qws, kws, vtws);
  attn_kernel<<<dim3(S_ / 64, B_ * NH_), 256, 0, stream>>>(qws, kws, vtws, attn_out);
  proj_gemm<<<dim3(H_ / 128, M_ / 128), 256, 0, stream>>>(attn_out, wprojt, proj_b, x, out);
}